// Round 12
// baseline (2371.791 us; speedup 1.0000x reference)
//
#include <hip/hip_runtime.h>
#include <hip/hip_bf16.h>

// STDP IF-neuron network, T=50 sequential steps. Lockstep persistent v9.
// x_seq [50,256,1024] f32, weight [2048,1024] f32 -> spike_trace [256,2048] f32.
//
// Round-10 analysis: 128 blocks each stream the full 2MB packed x-slice per
// step -> 256MB/step of L3 reads / 28.3us = 9.05 TB/s == L3 BW saturation.
// The 16 blocks of an XCD read IDENTICAL data; the 2MB step working set fits
// the 4MB per-XCD L2 -- but unsynchronized blocks drift and thrash L3.
// v9 = round-10 kernel + two grid-wide barriers per step (lockstep => L2
// sharing) + fragment-order LDS from v11 (42.7M -> ~3M bank conflicts).
// No data exchange between blocks -> numerics bit-identical to rounds 4-11.
//
// Barrier: sense-free monotonic generation (target = 2t+1, 2t+2), atomic
// counter+gen in ws, memset each launch (graph-replay safe). 128 blocks,
// 72KB LDS, 512 thr -> all co-resident; spins cannot starve.

#define T_STEPS 50
#define BATCH   256
#define DIM     1024
#define HID     2048
#define HT      16
#define LR_OVER_B (0.005f / 256.0f)

// LDS: whF 32KB | wlF 32KB | slF 8KB (fragment order, chunk-major)
#define SMEM_BYTES (32768 + 32768 + 8192)

typedef __attribute__((ext_vector_type(8))) short short8v;
typedef __attribute__((ext_vector_type(4))) float f32x4;

static __device__ __forceinline__ ushort f32_to_bf16u(float f) {
    __hip_bfloat16 h = __float2bfloat16(f);
    return __builtin_bit_cast(unsigned short, h);
}
static __device__ __forceinline__ float bf16u_to_f32(ushort u) {
    __hip_bfloat16 h = __builtin_bit_cast(__hip_bfloat16, u);
    return __bfloat162float(h);
}

#define MFMA_B16 __builtin_amdgcn_mfma_f32_16x16x32_bf16

// ---------------- prep A: fwd fragment packing (r10, unchanged) -----------
// XF[t][bt=0..15][c=0..31][h=0..1][lane=0..63][8] ushorts.
__global__ __launch_bounds__(256) void prep_fwd(
    const float* __restrict__ x, ushort* __restrict__ XF)
{
    __shared__ float xs[16 * 1024];
    const int t  = blockIdx.x >> 4;
    const int bt = blockIdx.x & 15;
    const float* xrow = x + ((size_t)t * BATCH + bt * 16) * DIM;
    for (int i = threadIdx.x; i < 16 * 1024 / 4; i += 256)
        ((float4*)xs)[i] = ((const float4*)xrow)[i];
    __syncthreads();

    ushort* outb = XF + ((size_t)t * 16 + bt) * (32 * 2 * 512);
    for (int item = threadIdx.x; item < 32 * 64; item += 256) {
        const int c = item >> 6;
        const int l = item & 63;
        const int row = l & 15;
        const int col = c * 32 + (l >> 4) * 8;
        short8v hv, lv;
#pragma unroll
        for (int j = 0; j < 8; ++j) {
            float v = xs[row * 1024 + col + j];
            ushort h = f32_to_bf16u(v);
            hv[j] = (short)h;
            lv[j] = (short)f32_to_bf16u(v - bf16u_to_f32(h));
        }
        *(short8v*)(outb + ((size_t)c * 2 + 0) * 512 + l * 8) = hv;
        *(short8v*)(outb + ((size_t)c * 2 + 1) * 512 + l * 8) = lv;
    }
}

// ---------------- prep B: wupd fragment packing (r10, unchanged) ----------
// XW[t][dt=0..63][c=0..7][h=0..1][lane=0..63][8] ushorts.
__global__ __launch_bounds__(256) void prep_wupd(
    const float* __restrict__ x, ushort* __restrict__ XW)
{
    __shared__ float xs[256 * 16];
    const int t  = blockIdx.x >> 6;
    const int dt = blockIdx.x & 63;
    {
        const int b = threadIdx.x;
        const float* src = x + ((size_t)t * BATCH + b) * DIM + dt * 16;
#pragma unroll
        for (int q = 0; q < 4; ++q)
            ((float4*)&xs[b * 16])[q] = ((const float4*)src)[q];
    }
    __syncthreads();

    ushort* outb = XW + ((size_t)t * 64 + dt) * (8 * 2 * 512);
    for (int item = threadIdx.x; item < 8 * 64; item += 256) {
        const int c = item >> 6;
        const int l = item & 63;
        const int drow = l & 15;
        const int bbase = c * 32 + (l >> 4) * 8;
        short8v hv, lv;
#pragma unroll
        for (int j = 0; j < 8; ++j) {
            float v = xs[(bbase + j) * 16 + drow];
            ushort h = f32_to_bf16u(v);
            hv[j] = (short)h;
            lv[j] = (short)f32_to_bf16u(v - bf16u_to_f32(h));
        }
        *(short8v*)(outb + ((size_t)c * 2 + 0) * 512 + l * 8) = hv;
        *(short8v*)(outb + ((size_t)c * 2 + 1) * 512 + l * 8) = lv;
    }
}

// ---------------- grid barrier (all 128 blocks co-resident) ---------------
static __device__ __forceinline__ void grid_bar(
    unsigned* cnt, unsigned* gen, unsigned target, int tid)
{
    __syncthreads();
    if (tid == 0) {
        unsigned old = __hip_atomic_fetch_add(cnt, 1u, __ATOMIC_ACQ_REL,
                                              __HIP_MEMORY_SCOPE_AGENT);
        if (old == 127u) {
            __hip_atomic_store(cnt, 0u, __ATOMIC_RELAXED,
                               __HIP_MEMORY_SCOPE_AGENT);
            __hip_atomic_store(gen, target, __ATOMIC_RELEASE,
                               __HIP_MEMORY_SCOPE_AGENT);
        } else {
            while (__hip_atomic_load(gen, __ATOMIC_ACQUIRE,
                                     __HIP_MEMORY_SCOPE_AGENT) < target)
                __builtin_amdgcn_s_sleep(1);
        }
    }
    __syncthreads();
}

// ---------------- THE lockstep persistent kernel --------------------------
__global__ __launch_bounds__(512, 2) void stdp_sync(
    const ushort* __restrict__ XF, const ushort* __restrict__ XW,
    const float* __restrict__ weight, float* __restrict__ out,
    unsigned* __restrict__ bar)           // [0]=cnt, [1]=gen (memset 0)
{
    extern __shared__ char smem[];
    ushort* whF = (ushort*)smem;          // 32 chunks x 512 us (frag order)
    ushort* wlF = whF + 32 * 512;
    ushort* slF = wlF + 32 * 512;         // 8 chunks x 512 us

    const int tid  = threadIdx.x;
    const int lane = tid & 63;
    const int w    = tid >> 6;            // wave 0..7
    const int h0   = blockIdx.x * HT;

    const int fr = lane & 15;             // h index within slab
    const int rq = (lane >> 4) * 4;       // D-fragment row base

    // ---- init: full-W bf16 frags -> LDS (wave w: chunks 4w..4w+3) ----
#pragma unroll
    for (int q = 0; q < 4; ++q) {
        const int c   = w * 4 + q;
        const int row = lane & 15;
        const int col = c * 32 + (lane >> 4) * 8;
        const float* src = &weight[(size_t)(h0 + row) * DIM + col];
        short8v hv, lv;
#pragma unroll
        for (int j = 0; j < 8; ++j) {
            float v = src[j];
            ushort h = f32_to_bf16u(v);
            hv[j] = (short)h;
            lv[j] = (short)f32_to_bf16u(v - bf16u_to_f32(h));
        }
        *(short8v*)&whF[c * 512 + lane * 8] = hv;
        *(short8v*)&wlF[c * 512 + lane * 8] = lv;
    }
    // ---- W fp32 master in registers: lane owns h=h0+fr, d=w*128+tile*16+rq ----
    f32x4 wreg[8];
#pragma unroll
    for (int tile = 0; tile < 8; ++tile) {
        const int d = w * 128 + tile * 16 + rq;
        float4 wv = *(const float4*)&weight[(size_t)(h0 + fr) * DIM + d];
        wreg[tile][0] = wv.x; wreg[tile][1] = wv.y;
        wreg[tile][2] = wv.z; wreg[tile][3] = wv.w;
    }
    __syncthreads();

    const f32x4 z4 = {0.f, 0.f, 0.f, 0.f};
    f32x4 vmem[2] = {z4, z4};
    f32x4 trc[2]  = {z4, z4};

    for (int t = 0; t < T_STEPS; ++t) {
        const ushort* xft = XF + (size_t)t * (16 * 32 * 2 * 512);

        // ============ fwd: mem = x @ W^T (3-product split) ================
        // wave w owns b-tiles {2w, 2w+1}; dense 64KB stream per tile.
#pragma unroll
        for (int bt = 0; bt < 2; ++bt) {
            f32x4 acc = z4;
            const ushort* wbase = xft + (size_t)(w * 2 + bt) * (32 * 2 * 512)
                                + lane * 8;
            short8v GA[4][2];
#pragma unroll 1
            for (int g = 0; g < 8; ++g) {
#pragma unroll
                for (int c = 0; c < 4; ++c) {
                    const int cc = g * 4 + c;
                    GA[c][0] = *(const short8v*)(wbase + ((size_t)cc * 2 + 0) * 512);
                    GA[c][1] = *(const short8v*)(wbase + ((size_t)cc * 2 + 1) * 512);
                }
#pragma unroll
                for (int c = 0; c < 4; ++c) {
                    const int cc = g * 4 + c;
                    short8v bh = *(const short8v*)&whF[cc * 512 + lane * 8];
                    short8v bl = *(const short8v*)&wlF[cc * 512 + lane * 8];
                    acc = MFMA_B16(GA[c][0], bh, acc, 0, 0, 0);
                    acc = MFMA_B16(GA[c][0], bl, acc, 0, 0, 0);
                    acc = MFMA_B16(GA[c][1], bh, acc, 0, 0, 0);
                }
            }

            // ---- IF update + s frag store (b = w*32 + bt*16 + rq + j) ----
            ushort4 sq; ushort* sp = &sq.x;
#pragma unroll
            for (int j = 0; j < 4; ++j) {
                float nv = vmem[bt][j] + acc[j];
                bool fire = (nv >= 1.0f);
                vmem[bt][j] = fire ? 0.0f : nv;
                trc[bt][j] += fire ? 1.0f : 0.0f;
                sp[j] = fire ? (ushort)0x3F80 : (ushort)0;
            }
            const int l_s = fr | ((bt * 2 + (rq >> 3)) << 4);
            *(ushort4*)&slF[w * 512 + l_s * 8 + (rq & 4)] = sq;
        }

        if (t >= T_STEPS - 1) break;   // last step: no wupd

        grid_bar(&bar[0], &bar[1], (unsigned)(2 * t + 1), tid);

        // ============ wupd: dwT = xT @ s^T, W += lr/B * dw ================
        {
            const ushort* xwt = XW + (size_t)t * (64 * 8 * 2 * 512);
            short8v HA[4][2];
#pragma unroll
            for (int tile = 0; tile < 8; ++tile) {
                f32x4 du = z4;
                const ushort* tbase = xwt + (size_t)(w * 8 + tile) * (8 * 2 * 512)
                                    + lane * 8;
#pragma unroll 1
                for (int half = 0; half < 2; ++half) {
#pragma unroll
                    for (int c2 = 0; c2 < 4; ++c2) {
                        const int cc = half * 4 + c2;
                        HA[c2][0] = *(const short8v*)(tbase + ((size_t)cc * 2 + 0) * 512);
                        HA[c2][1] = *(const short8v*)(tbase + ((size_t)cc * 2 + 1) * 512);
                    }
#pragma unroll
                    for (int c2 = 0; c2 < 4; ++c2) {
                        const int cc = half * 4 + c2;
                        short8v sf = *(const short8v*)&slF[cc * 512 + lane * 8];
                        du = MFMA_B16(HA[c2][0], sf, du, 0, 0, 0);
                        du = MFMA_B16(HA[c2][1], sf, du, 0, 0, 0);
                    }
                }
                // ---- W master update + re-split (frag-order store) ----
                ushort4 hi4, lo4;
                ushort* hp = &hi4.x; ushort* lp = &lo4.x;
#pragma unroll
                for (int j = 0; j < 4; ++j) {
                    float wv = fmaf(LR_OVER_B, du[j], wreg[tile][j]);
                    wreg[tile][j] = wv;
                    ushort hb = f32_to_bf16u(wv);
                    hp[j] = hb;
                    lp[j] = f32_to_bf16u(wv - bf16u_to_f32(hb));
                }
                const int c_w = w * 4 + (tile >> 1);
                const int l_w = fr | (((tile & 1) * 2 + (rq >> 3)) << 4);
                const int off = c_w * 512 + l_w * 8 + (rq & 4);
                *(ushort4*)&whF[off] = hi4;
                *(ushort4*)&wlF[off] = lo4;
                __builtin_amdgcn_sched_barrier(0);
            }
        }

        grid_bar(&bar[0], &bar[1], (unsigned)(2 * t + 2), tid);
    }

    // ---- write trace (registers) to d_out [B,H] ----
#pragma unroll
    for (int bt = 0; bt < 2; ++bt) {
#pragma unroll
        for (int j = 0; j < 4; ++j) {
            int b = w * 32 + bt * 16 + rq + j;
            out[(size_t)b * HID + h0 + fr] = trc[bt][j];
        }
    }
}

// ---------------- fallback fp32 kernels (round-0, small ws) ---------------
#define BK 16
__global__ __launch_bounds__(256) void stdp_fwd_if(
    const float* __restrict__ x, const float* __restrict__ w,
    float* __restrict__ v, float* __restrict__ s, float* __restrict__ trace)
{
    __shared__ float as[BK][64];
    __shared__ float bs[BK][64];
    const int tid = threadIdx.x;
    const int tx = tid & 15, ty = tid >> 4;
    const int b0 = blockIdx.y * 64, h0 = blockIdx.x * 64;
    const int row = tid >> 2, kq = (tid & 3) * 4;
    float acc[4][4] = {};
    for (int k0 = 0; k0 < DIM; k0 += BK) {
        float4 ga = *(const float4*)&x[(size_t)(b0 + row) * DIM + k0 + kq];
        float4 gb = *(const float4*)&w[(size_t)(h0 + row) * DIM + k0 + kq];
        __syncthreads();
        as[kq + 0][row] = ga.x; as[kq + 1][row] = ga.y;
        as[kq + 2][row] = ga.z; as[kq + 3][row] = ga.w;
        bs[kq + 0][row] = gb.x; bs[kq + 1][row] = gb.y;
        bs[kq + 2][row] = gb.z; bs[kq + 3][row] = gb.w;
        __syncthreads();
#pragma unroll
        for (int kk = 0; kk < BK; ++kk) {
            float4 af = *(const float4*)&as[kk][ty * 4];
            float4 bf = *(const float4*)&bs[kk][tx * 4];
            float av[4] = {af.x, af.y, af.z, af.w};
            float bv[4] = {bf.x, bf.y, bf.z, bf.w};
#pragma unroll
            for (int m = 0; m < 4; ++m)
#pragma unroll
                for (int n = 0; n < 4; ++n)
                    acc[m][n] = fmaf(av[m], bv[n], acc[m][n]);
        }
    }
#pragma unroll
    for (int m = 0; m < 4; ++m) {
        size_t idx = (size_t)(b0 + ty * 4 + m) * HID + h0 + tx * 4;
        float4 vv = *(float4*)&v[idx];
        float4 tr = *(float4*)&trace[idx];
        float4 sv;
        float* vvp = &vv.x; float* trp = &tr.x; float* svp = &sv.x;
#pragma unroll
        for (int n = 0; n < 4; ++n) {
            float nv = vvp[n] + acc[m][n];
            float sp = (nv >= 1.0f) ? 1.0f : 0.0f;
            vvp[n] = (nv >= 1.0f) ? 0.0f : nv;
            svp[n] = sp; trp[n] += sp;
        }
        *(float4*)&v[idx] = vv;
        *(float4*)&s[idx] = sv;
        *(float4*)&trace[idx] = tr;
    }
}

__global__ __launch_bounds__(256) void stdp_wupd(
    const float* __restrict__ x, const float* __restrict__ s,
    float* __restrict__ w)
{
    __shared__ float ss[BK][64];
    __shared__ float xs[BK][64];
    const int tid = threadIdx.x;
    const int tx = tid & 15, ty = tid >> 4;
    const int h0 = blockIdx.y * 64, d0 = blockIdx.x * 64;
    const int krow = tid >> 4, c4 = (tid & 15) * 4;
    float acc[4][4] = {};
    for (int bk0 = 0; bk0 < BATCH; bk0 += BK) {
        float4 gs = *(const float4*)&s[(size_t)(bk0 + krow) * HID + h0 + c4];
        float4 gx = *(const float4*)&x[(size_t)(bk0 + krow) * DIM + d0 + c4];
        __syncthreads();
        *(float4*)&ss[krow][c4] = gs;
        *(float4*)&xs[krow][c4] = gx;
        __syncthreads();
#pragma unroll
        for (int kk = 0; kk < BK; ++kk) {
            float4 af = *(const float4*)&ss[kk][ty * 4];
            float4 bf = *(const float4*)&xs[kk][tx * 4];
            float av[4] = {af.x, af.y, af.z, af.w};
            float bv[4] = {bf.x, bf.y, bf.z, bf.w};
#pragma unroll
            for (int m = 0; m < 4; ++m)
#pragma unroll
                for (int n = 0; n < 4; ++n)
                    acc[m][n] = fmaf(av[m], bv[n], acc[m][n]);
        }
    }
#pragma unroll
    for (int m = 0; m < 4; ++m) {
        size_t idx = (size_t)(h0 + ty * 4 + m) * DIM + d0 + tx * 4;
        float4 wv = *(float4*)&w[idx];
        wv.x = fmaf(LR_OVER_B, acc[m][0], wv.x);
        wv.y = fmaf(LR_OVER_B, acc[m][1], wv.y);
        wv.z = fmaf(LR_OVER_B, acc[m][2], wv.z);
        wv.w = fmaf(LR_OVER_B, acc[m][3], wv.w);
        *(float4*)&w[idx] = wv;
    }
}

extern "C" void kernel_launch(void* const* d_in, const int* in_sizes, int n_in,
                              void* d_out, int out_size, void* d_ws, size_t ws_size,
                              hipStream_t stream) {
    (void)in_sizes; (void)n_in;
    const float* x_seq  = (const float*)d_in[0];   // [T, B, D]
    const float* weight = (const float*)d_in[1];   // [H, D]
    float* out = (float*)d_out;                    // [B, H]

    const size_t WN = (size_t)HID * DIM;
    const size_t BH = (size_t)BATCH * HID;
    const size_t XN = (size_t)T_STEPS * BATCH * DIM;  // 13107200

    // ws: XF (2XN us) | XW (2XN us) | bar (2 u32)
    const size_t need = 8 * XN + 8;

    if (ws_size >= need) {
        ushort* XF = (ushort*)d_ws;
        ushort* XW = XF + 2 * XN;
        unsigned* bar = (unsigned*)(XW + 2 * XN);

        hipMemsetAsync(bar, 0, 8, stream);         // replay-safe barrier reset
        prep_fwd<<<T_STEPS * 16, 256, 0, stream>>>(x_seq, XF);
        prep_wupd<<<T_STEPS * 64, 256, 0, stream>>>(x_seq, XW);

        hipFuncSetAttribute(reinterpret_cast<const void*>(&stdp_sync),
                            hipFuncAttributeMaxDynamicSharedMemorySize,
                            SMEM_BYTES);
        stdp_sync<<<HID / HT, 512, SMEM_BYTES, stream>>>(
            XF, XW, weight, out, bar);
    } else {
        // fallback: fp32 VALU path (needs ~12.6 MB)
        float* w = (float*)d_ws;
        float* v = w + WN;
        float* s = v + BH;
        hipMemcpyAsync(w, weight, WN * 4, hipMemcpyDeviceToDevice, stream);
        hipMemsetAsync(v, 0, BH * 4, stream);
        hipMemsetAsync(out, 0, (size_t)out_size * 4, stream);
        dim3 blkA(256), grdA(HID / 64, BATCH / 64);
        dim3 blkB(256), grdB(DIM / 64, HID / 64);
        for (int t = 0; t < T_STEPS; ++t) {
            const float* xt = x_seq + (size_t)t * BATCH * DIM;
            stdp_fwd_if<<<grdA, blkA, 0, stream>>>(xt, w, v, s, out);
            if (t < T_STEPS - 1) {
                stdp_wupd<<<grdB, blkB, 0, stream>>>(xt, s, w);
            }
        }
    }
}

// Round 13
// 1009.244 us; speedup vs baseline: 2.3501x; 2.3501x over previous
//
#include <hip/hip_runtime.h>
#include <hip/hip_bf16.h>

// STDP IF-neuron network, T=50 sequential steps. Persistent v10 (16-wave).
// x_seq [50,256,1024] f32, weight [2048,1024] f32 -> spike_trace [256,2048] f32.
//
// Round-12 falsification: lockstep barrier cost 19us/step, FETCH unchanged
// -> no L3 thrash existed. Round-10's 28.3us/step = 70 GB/s/CU ingest at
// 2 waves/SIMD, latency-bound (both pipes <8%). v10 doubles TLP: 1024-thr
// blocks (16 waves, 4/SIMD). Fits because W fp32 master moves regs->LDS
// (frag-ordered, lane-linear float4) so per-thread state ~54 VGPR fits
// even the 64-VGPR allocation 1024-thr blocks get (r6/r7 spills were
// ~90-VGPR state). LDS 136KB: wfs 64 | wh 32 | wl 32 | s 8. 1 block/CU.
// All LDS accesses lane-linear (frag order, r12-proven: 42.7M->3.6M
// conflicts). No grid barrier (r12: -19us/step), no exchange (r11: WRITE
// explosion). Product set + chain order identical -> bit-identical output.

#define T_STEPS 50
#define BATCH   256
#define DIM     1024
#define HID     2048
#define HT      16
#define LR_OVER_B (0.005f / 256.0f)

// LDS: wfs 64KB | whF 32KB | wlF 32KB | slF 8KB
#define SMEM_BYTES (65536 + 32768 + 32768 + 8192)

typedef __attribute__((ext_vector_type(8))) short short8v;
typedef __attribute__((ext_vector_type(4))) float f32x4;

static __device__ __forceinline__ ushort f32_to_bf16u(float f) {
    __hip_bfloat16 h = __float2bfloat16(f);
    return __builtin_bit_cast(unsigned short, h);
}
static __device__ __forceinline__ float bf16u_to_f32(ushort u) {
    __hip_bfloat16 h = __builtin_bit_cast(__hip_bfloat16, u);
    return __bfloat162float(h);
}

#define MFMA_B16 __builtin_amdgcn_mfma_f32_16x16x32_bf16

// ---------------- prep A: fwd fragment packing (r10, unchanged) -----------
// XF[t][bt=0..15][c=0..31][h=0..1][lane=0..63][8] ushorts.
__global__ __launch_bounds__(256) void prep_fwd(
    const float* __restrict__ x, ushort* __restrict__ XF)
{
    __shared__ float xs[16 * 1024];
    const int t  = blockIdx.x >> 4;
    const int bt = blockIdx.x & 15;
    const float* xrow = x + ((size_t)t * BATCH + bt * 16) * DIM;
    for (int i = threadIdx.x; i < 16 * 1024 / 4; i += 256)
        ((float4*)xs)[i] = ((const float4*)xrow)[i];
    __syncthreads();

    ushort* outb = XF + ((size_t)t * 16 + bt) * (32 * 2 * 512);
    for (int item = threadIdx.x; item < 32 * 64; item += 256) {
        const int c = item >> 6;
        const int l = item & 63;
        const int row = l & 15;
        const int col = c * 32 + (l >> 4) * 8;
        short8v hv, lv;
#pragma unroll
        for (int j = 0; j < 8; ++j) {
            float v = xs[row * 1024 + col + j];
            ushort h = f32_to_bf16u(v);
            hv[j] = (short)h;
            lv[j] = (short)f32_to_bf16u(v - bf16u_to_f32(h));
        }
        *(short8v*)(outb + ((size_t)c * 2 + 0) * 512 + l * 8) = hv;
        *(short8v*)(outb + ((size_t)c * 2 + 1) * 512 + l * 8) = lv;
    }
}

// ---------------- prep B: wupd fragment packing (r10, unchanged) ----------
// XW[t][dt=0..63][c=0..7][h=0..1][lane=0..63][8] ushorts.
__global__ __launch_bounds__(256) void prep_wupd(
    const float* __restrict__ x, ushort* __restrict__ XW)
{
    __shared__ float xs[256 * 16];
    const int t  = blockIdx.x >> 6;
    const int dt = blockIdx.x & 63;
    {
        const int b = threadIdx.x;
        const float* src = x + ((size_t)t * BATCH + b) * DIM + dt * 16;
#pragma unroll
        for (int q = 0; q < 4; ++q)
            ((float4*)&xs[b * 16])[q] = ((const float4*)src)[q];
    }
    __syncthreads();

    ushort* outb = XW + ((size_t)t * 64 + dt) * (8 * 2 * 512);
    for (int item = threadIdx.x; item < 8 * 64; item += 256) {
        const int c = item >> 6;
        const int l = item & 63;
        const int drow = l & 15;
        const int bbase = c * 32 + (l >> 4) * 8;
        short8v hv, lv;
#pragma unroll
        for (int j = 0; j < 8; ++j) {
            float v = xs[(bbase + j) * 16 + drow];
            ushort h = f32_to_bf16u(v);
            hv[j] = (short)h;
            lv[j] = (short)f32_to_bf16u(v - bf16u_to_f32(h));
        }
        *(short8v*)(outb + ((size_t)c * 2 + 0) * 512 + l * 8) = hv;
        *(short8v*)(outb + ((size_t)c * 2 + 1) * 512 + l * 8) = lv;
    }
}

// ---------------- THE 16-wave persistent kernel ---------------------------
__global__ __launch_bounds__(1024, 1) void stdp_big(
    const ushort* __restrict__ XF, const ushort* __restrict__ XW,
    const float* __restrict__ weight, float* __restrict__ out)
{
    extern __shared__ char smem[];
    float*  wfs = (float*)smem;               // [64 dt][64 lane][4] fp32 master
    ushort* whF = (ushort*)(smem + 65536);    // 32 chunks x 512 us (frag order)
    ushort* wlF = whF + 32 * 512;
    ushort* slF = wlF + 32 * 512;             // 8 chunks x 512 us

    const int tid  = threadIdx.x;
    const int lane = tid & 63;
    const int w    = tid >> 6;                // wave 0..15
    const int h0   = blockIdx.x * HT;

    const int fr = lane & 15;                 // h index within slab
    const int rq = (lane >> 4) * 4;           // D-fragment row base

    // ---- init whF/wlF: 32 chunks x 64 lane-slots (2 per thread) ----
    for (int i = tid; i < 32 * 64; i += 1024) {
        const int cc  = i >> 6;
        const int l   = i & 63;
        const int row = l & 15;
        const int col = cc * 32 + (l >> 4) * 8;
        const float* src = &weight[(size_t)(h0 + row) * DIM + col];
        short8v hv, lv;
#pragma unroll
        for (int j = 0; j < 8; ++j) {
            float v = src[j];
            ushort h = f32_to_bf16u(v);
            hv[j] = (short)h;
            lv[j] = (short)f32_to_bf16u(v - bf16u_to_f32(h));
        }
        *(short8v*)&whF[cc * 512 + l * 8] = hv;
        *(short8v*)&wlF[cc * 512 + l * 8] = lv;
    }
    // ---- init wfs: (dt, lane) owns h=lane&15, d=dt*16+((lane>>4)*4)+j ----
    for (int i = tid; i < 64 * 64; i += 1024) {
        const int dt = i >> 6;
        const int l  = i & 63;
        const int h  = l & 15;
        const int d  = dt * 16 + (l >> 4) * 4;
        *(float4*)&wfs[(size_t)i * 4] =
            *(const float4*)&weight[(size_t)(h0 + h) * DIM + d];
    }
    __syncthreads();

    const f32x4 z4 = {0.f, 0.f, 0.f, 0.f};
    f32x4 vmem = z4;
    f32x4 trc  = z4;

    for (int t = 0; t < T_STEPS; ++t) {
        const ushort* xft = XF + (size_t)t * (16 * 32 * 2 * 512);

        // ============ fwd: mem = x @ W^T (3-product split) ================
        // wave w owns b-tile w; dense 64KB stream.
        {
            f32x4 acc = z4;
            const ushort* wbase = xft + (size_t)w * (32 * 2 * 512) + lane * 8;
            short8v GA[4][2];
#pragma unroll 1
            for (int g = 0; g < 8; ++g) {
#pragma unroll
                for (int c = 0; c < 4; ++c) {
                    const int cc = g * 4 + c;
                    GA[c][0] = *(const short8v*)(wbase + ((size_t)cc * 2 + 0) * 512);
                    GA[c][1] = *(const short8v*)(wbase + ((size_t)cc * 2 + 1) * 512);
                }
#pragma unroll
                for (int c = 0; c < 4; ++c) {
                    const int cc = g * 4 + c;
                    short8v bh = *(const short8v*)&whF[cc * 512 + lane * 8];
                    short8v bl = *(const short8v*)&wlF[cc * 512 + lane * 8];
                    acc = MFMA_B16(GA[c][0], bh, acc, 0, 0, 0);
                    acc = MFMA_B16(GA[c][0], bl, acc, 0, 0, 0);
                    acc = MFMA_B16(GA[c][1], bh, acc, 0, 0, 0);
                }
            }

            // ---- IF update + s frag store (b = w*16 + rq + j) ----
            ushort4 sq; ushort* sp = &sq.x;
#pragma unroll
            for (int j = 0; j < 4; ++j) {
                float nv = vmem[j] + acc[j];
                bool fire = (nv >= 1.0f);
                vmem[j] = fire ? 0.0f : nv;
                trc[j] += fire ? 1.0f : 0.0f;
                sp[j] = fire ? (ushort)0x3F80 : (ushort)0;
            }
            const int l_s = fr | (((w & 1) * 2 + (rq >> 3)) << 4);
            *(ushort4*)&slF[(w >> 1) * 512 + l_s * 8 + (rq & 4)] = sq;
        }

        if (t >= T_STEPS - 1) break;   // last step: no wupd

        __syncthreads();               // barrier 1: s complete; W-reads done

        // ============ wupd: dwT = xT @ s^T, W += lr/B * dw ================
        // wave w owns d-tiles 4w..4w+3; dense 16KB stream per tile.
        {
            const ushort* xwt = XW + (size_t)t * (64 * 8 * 2 * 512);
            short8v HA[4][2];
#pragma unroll
            for (int q = 0; q < 4; ++q) {
                const int dt = w * 4 + q;
                f32x4 du = z4;
                const ushort* tbase = xwt + (size_t)dt * (8 * 2 * 512) + lane * 8;
#pragma unroll 1
                for (int half = 0; half < 2; ++half) {
#pragma unroll
                    for (int c2 = 0; c2 < 4; ++c2) {
                        const int cc = half * 4 + c2;
                        HA[c2][0] = *(const short8v*)(tbase + ((size_t)cc * 2 + 0) * 512);
                        HA[c2][1] = *(const short8v*)(tbase + ((size_t)cc * 2 + 1) * 512);
                    }
#pragma unroll
                    for (int c2 = 0; c2 < 4; ++c2) {
                        const int cc = half * 4 + c2;
                        short8v sf = *(const short8v*)&slF[cc * 512 + lane * 8];
                        du = MFMA_B16(HA[c2][0], sf, du, 0, 0, 0);
                        du = MFMA_B16(HA[c2][1], sf, du, 0, 0, 0);
                    }
                }
                // ---- W master update (LDS, lane-linear) + re-split ----
                float4* wp = (float4*)&wfs[((size_t)dt * 64 + lane) * 4];
                float4 wv = *wp;
                float* wvp = &wv.x;
                ushort4 hi4, lo4;
                ushort* hp = &hi4.x; ushort* lp = &lo4.x;
#pragma unroll
                for (int j = 0; j < 4; ++j) {
                    float nw = fmaf(LR_OVER_B, du[j], wvp[j]);
                    wvp[j] = nw;
                    ushort hb = f32_to_bf16u(nw);
                    hp[j] = hb;
                    lp[j] = f32_to_bf16u(nw - bf16u_to_f32(hb));
                }
                *wp = wv;
                const int l_w = fr | (((dt & 1) * 2 + (rq >> 3)) << 4);
                const int off = (dt >> 1) * 512 + l_w * 8 + (rq & 4);
                *(ushort4*)&whF[off] = hi4;
                *(ushort4*)&wlF[off] = lo4;
                __builtin_amdgcn_sched_barrier(0);
            }
        }

        __syncthreads();               // barrier 2: whF/wlF ready for next fwd
    }

    // ---- write trace (registers) to d_out [B,H]; b = w*16 + rq + j ----
#pragma unroll
    for (int j = 0; j < 4; ++j) {
        const int b = w * 16 + rq + j;
        out[(size_t)b * HID + h0 + fr] = trc[j];
    }
}

// ---------------- fallback fp32 kernels (round-0, small ws) ---------------
#define BK 16
__global__ __launch_bounds__(256) void stdp_fwd_if(
    const float* __restrict__ x, const float* __restrict__ w,
    float* __restrict__ v, float* __restrict__ s, float* __restrict__ trace)
{
    __shared__ float as[BK][64];
    __shared__ float bs[BK][64];
    const int tid = threadIdx.x;
    const int tx = tid & 15, ty = tid >> 4;
    const int b0 = blockIdx.y * 64, h0 = blockIdx.x * 64;
    const int row = tid >> 2, kq = (tid & 3) * 4;
    float acc[4][4] = {};
    for (int k0 = 0; k0 < DIM; k0 += BK) {
        float4 ga = *(const float4*)&x[(size_t)(b0 + row) * DIM + k0 + kq];
        float4 gb = *(const float4*)&w[(size_t)(h0 + row) * DIM + k0 + kq];
        __syncthreads();
        as[kq + 0][row] = ga.x; as[kq + 1][row] = ga.y;
        as[kq + 2][row] = ga.z; as[kq + 3][row] = ga.w;
        bs[kq + 0][row] = gb.x; bs[kq + 1][row] = gb.y;
        bs[kq + 2][row] = gb.z; bs[kq + 3][row] = gb.w;
        __syncthreads();
#pragma unroll
        for (int kk = 0; kk < BK; ++kk) {
            float4 af = *(const float4*)&as[kk][ty * 4];
            float4 bf = *(const float4*)&bs[kk][tx * 4];
            float av[4] = {af.x, af.y, af.z, af.w};
            float bv[4] = {bf.x, bf.y, bf.z, bf.w};
#pragma unroll
            for (int m = 0; m < 4; ++m)
#pragma unroll
                for (int n = 0; n < 4; ++n)
                    acc[m][n] = fmaf(av[m], bv[n], acc[m][n]);
        }
    }
#pragma unroll
    for (int m = 0; m < 4; ++m) {
        size_t idx = (size_t)(b0 + ty * 4 + m) * HID + h0 + tx * 4;
        float4 vv = *(float4*)&v[idx];
        float4 tr = *(float4*)&trace[idx];
        float4 sv;
        float* vvp = &vv.x; float* trp = &tr.x; float* svp = &sv.x;
#pragma unroll
        for (int n = 0; n < 4; ++n) {
            float nv = vvp[n] + acc[m][n];
            float sp = (nv >= 1.0f) ? 1.0f : 0.0f;
            vvp[n] = (nv >= 1.0f) ? 0.0f : nv;
            svp[n] = sp; trp[n] += sp;
        }
        *(float4*)&v[idx] = vv;
        *(float4*)&s[idx] = sv;
        *(float4*)&trace[idx] = tr;
    }
}

__global__ __launch_bounds__(256) void stdp_wupd(
    const float* __restrict__ x, const float* __restrict__ s,
    float* __restrict__ w)
{
    __shared__ float ss[BK][64];
    __shared__ float xs[BK][64];
    const int tid = threadIdx.x;
    const int tx = tid & 15, ty = tid >> 4;
    const int h0 = blockIdx.y * 64, d0 = blockIdx.x * 64;
    const int krow = tid >> 4, c4 = (tid & 15) * 4;
    float acc[4][4] = {};
    for (int bk0 = 0; bk0 < BATCH; bk0 += BK) {
        float4 gs = *(const float4*)&s[(size_t)(bk0 + krow) * HID + h0 + c4];
        float4 gx = *(const float4*)&x[(size_t)(bk0 + krow) * DIM + d0 + c4];
        __syncthreads();
        *(float4*)&ss[krow][c4] = gs;
        *(float4*)&xs[krow][c4] = gx;
        __syncthreads();
#pragma unroll
        for (int kk = 0; kk < BK; ++kk) {
            float4 af = *(const float4*)&ss[kk][ty * 4];
            float4 bf = *(const float4*)&xs[kk][tx * 4];
            float av[4] = {af.x, af.y, af.z, af.w};
            float bv[4] = {bf.x, bf.y, bf.z, bf.w};
#pragma unroll
            for (int m = 0; m < 4; ++m)
#pragma unroll
                for (int n = 0; n < 4; ++n)
                    acc[m][n] = fmaf(av[m], bv[n], acc[m][n]);
        }
    }
#pragma unroll
    for (int m = 0; m < 4; ++m) {
        size_t idx = (size_t)(h0 + ty * 4 + m) * DIM + d0 + tx * 4;
        float4 wv = *(float4*)&w[idx];
        wv.x = fmaf(LR_OVER_B, acc[m][0], wv.x);
        wv.y = fmaf(LR_OVER_B, acc[m][1], wv.y);
        wv.z = fmaf(LR_OVER_B, acc[m][2], wv.z);
        wv.w = fmaf(LR_OVER_B, acc[m][3], wv.w);
        *(float4*)&w[idx] = wv;
    }
}

extern "C" void kernel_launch(void* const* d_in, const int* in_sizes, int n_in,
                              void* d_out, int out_size, void* d_ws, size_t ws_size,
                              hipStream_t stream) {
    (void)in_sizes; (void)n_in;
    const float* x_seq  = (const float*)d_in[0];   // [T, B, D]
    const float* weight = (const float*)d_in[1];   // [H, D]
    float* out = (float*)d_out;                    // [B, H]

    const size_t WN = (size_t)HID * DIM;
    const size_t BH = (size_t)BATCH * HID;
    const size_t XN = (size_t)T_STEPS * BATCH * DIM;  // 13107200

    // ws: XF (2XN us) | XW (2XN us)
    const size_t need = 8 * XN;

    if (ws_size >= need) {
        ushort* XF = (ushort*)d_ws;
        ushort* XW = XF + 2 * XN;

        prep_fwd<<<T_STEPS * 16, 256, 0, stream>>>(x_seq, XF);
        prep_wupd<<<T_STEPS * 64, 256, 0, stream>>>(x_seq, XW);

        hipFuncSetAttribute(reinterpret_cast<const void*>(&stdp_big),
                            hipFuncAttributeMaxDynamicSharedMemorySize,
                            SMEM_BYTES);
        stdp_big<<<HID / HT, 1024, SMEM_BYTES, stream>>>(
            XF, XW, weight, out);
    } else {
        // fallback: fp32 VALU path (needs ~12.6 MB)
        float* w = (float*)d_ws;
        float* v = w + WN;
        float* s = v + BH;
        hipMemcpyAsync(w, weight, WN * 4, hipMemcpyDeviceToDevice, stream);
        hipMemsetAsync(v, 0, BH * 4, stream);
        hipMemsetAsync(out, 0, (size_t)out_size * 4, stream);
        dim3 blkA(256), grdA(HID / 64, BATCH / 64);
        dim3 blkB(256), grdB(DIM / 64, HID / 64);
        for (int t = 0; t < T_STEPS; ++t) {
            const float* xt = x_seq + (size_t)t * BATCH * DIM;
            stdp_fwd_if<<<grdA, blkA, 0, stream>>>(xt, w, v, s, out);
            if (t < T_STEPS - 1) {
                stdp_wupd<<<grdB, blkB, 0, stream>>>(xt, s, w);
            }
        }
    }
}